// Round 1
// 360.207 us; speedup vs baseline: 1.1273x; 1.1273x over previous
//
#include <hip/hip_runtime.h>
#include <stdint.h>

#define NPTS 8192
#define KNN 32
#define KPN 15
#define SCC 64
#define OUTC 256
#define R2F 0.0144f              /* radius^2: the reference's in_range mask */
#define INV_EXT (1.0f/0.096f)
#define SCAP 128                 /* per-query survivor cap */
#define NT 8                     /* points per kpconv block */

// ---- conv_in: 4 rows per thread (lane = channel), W read once per 4 rows ----
// Grid: 1024 blocks x 256 thr. Block = 16 rows (4 waves x 4 rows).
// W traffic /4 vs 1-row version; x loaded as float4.
__global__ __launch_bounds__(256) void conv_in_k(
    const float* __restrict__ src, const float* __restrict__ tgt,
    const float* __restrict__ W, const float* __restrict__ b,
    float* __restrict__ h)
{
  int t = threadIdx.x;
  int w = t >> 6, c = t & 63;
  int row = blockIdx.x*16 + w*4;          // 0..16383 = cloud*NPTS+n (no straddle)
  const float* x = (row >> 13) ? tgt : src;
  int n0 = row & 8191;
  const float4* x0 = (const float4*)(x + (size_t)n0*256);
  const float4* x1 = x0 + 64;
  const float4* x2 = x0 + 128;
  const float4* x3 = x0 + 192;
  float bc = b[c];
  float a0 = bc, a1 = bc, a2 = bc, a3 = bc;
  #pragma unroll 4
  for (int k4 = 0; k4 < 64; ++k4) {
    float4 v0 = x0[k4], v1 = x1[k4], v2 = x2[k4], v3 = x3[k4];
    const float* wp = W + (size_t)k4*4*64 + c;
    float w0 = wp[0], w1 = wp[64], w2 = wp[128], w3 = wp[192];
    a0 = fmaf(v0.x,w0,a0); a0 = fmaf(v0.y,w1,a0); a0 = fmaf(v0.z,w2,a0); a0 = fmaf(v0.w,w3,a0);
    a1 = fmaf(v1.x,w0,a1); a1 = fmaf(v1.y,w1,a1); a1 = fmaf(v1.z,w2,a1); a1 = fmaf(v1.w,w3,a1);
    a2 = fmaf(v2.x,w0,a2); a2 = fmaf(v2.y,w1,a2); a2 = fmaf(v2.z,w2,a2); a2 = fmaf(v2.w,w3,a2);
    a3 = fmaf(v3.x,w0,a3); a3 = fmaf(v3.y,w1,a3); a3 = fmaf(v3.z,w2,a3); a3 = fmaf(v3.w,w3,a3);
  }
  float* hr = h + (size_t)row*SCC + c;
  hr[0] = a0; hr[64] = a1; hr[128] = a2; hr[192] = a3;
}

// ---- kNN: one wave per query, LDS-atomic gather + wave rank-select (unchanged)
__global__ __launch_bounds__(256) void knn_par(
    const float* __restrict__ cA, const float* __restrict__ cB,
    short* __restrict__ fidx)
{
  __shared__ float cbuf[2048*3];                  // 24 KB
  __shared__ unsigned long long surv[4][SCAP];    // 4 KB
  __shared__ unsigned int scnt[4];
  int b = blockIdx.x;                // 4096 blocks: cloud(1)|qg(11)
  int cloud = b >> 11;
  int qg = b & 2047;
  const float* coords = cloud ? cB : cA;
  int t = threadIdx.x;
  int w = t >> 6, lane = t & 63;
  int q = qg*4 + w;
  float qx = coords[(size_t)q*3];
  float qy = coords[(size_t)q*3+1];
  float qz = coords[(size_t)q*3+2];
  if (t < 4) scnt[t] = 0u;
  for (int chunk = 0; chunk < 4; ++chunk) {
    __syncthreads();
    int base = chunk*2048;
    const float* gsrc = coords + (size_t)base*3;
    for (int i = t; i < 2048*3; i += 256) cbuf[i] = gsrc[i];
    __syncthreads();
    #pragma unroll 8
    for (int j = 0; j < 32; ++j) {
      int i = lane + 64*j;
      float dx = qx - cbuf[i*3];
      float dy = qy - cbuf[i*3+1];
      float dz = qz - cbuf[i*3+2];
      float d2 = fmaf(dx, dx, fmaf(dy, dy, dz*dz));
      if (d2 <= R2F) {
        unsigned int pos = atomicAdd(&scnt[w], 1u);
        if (pos < SCAP)
          surv[w][pos] = ((unsigned long long)__float_as_uint(d2) << 32)
                         | (unsigned int)(base + i);
      }
    }
  }
  __syncthreads();
  int C = (int)scnt[w]; if (C > SCAP) C = SCAP;
  unsigned long long k0 = (lane      < C) ? surv[w][lane]      : ~0ULL;
  unsigned long long k1 = (lane + 64 < C) ? surv[w][lane + 64] : ~0ULL;
  int r0 = 0, r1 = 0;
  for (int j = 0; j < C; ++j) {
    unsigned long long kj = surv[w][j];       // same addr all lanes: broadcast
    r0 += (kj < k0);
    r1 += (kj < k1);
  }
  size_t g = (size_t)cloud*NPTS + q;
  if (k0 != ~0ULL && r0 < KNN) fidx[g*KNN + r0] = (short)(k0 & 0xffffu);
  if (k1 != ~0ULL && r1 < KNN) fidx[g*KNN + r1] = (short)(k1 & 0xffffu);
  if (lane >= C && lane < KNN) fidx[g*KNN + lane] = (short)-1;  // sentinel fill
}

// ---- fused KPConv + conv_out + bias + BN partial stats, 8 points/block -------
// Phase A (per wave = per point): agg[pt][j=p*64+c] in LDS.
// Phase B: h2 = agg @ Wkp, 8 waves x 2-row lane-groups per 64-row chunk.
//          W_kp staged per chunk (240 KB/block amortized over 8 points).
// Epilogue: y = h2 @ W_out + b_out written straight to global; per-block
//          partial sums atomicAdd'ed into stats (replaces bn_stats kernel).
// LDS 63 KB -> 2 blocks/CU (16 waves/CU).
__global__ __launch_bounds__(512) void kpconv_fused(
    const float* __restrict__ cA, const float* __restrict__ cB,
    const float* __restrict__ kpts, const short* __restrict__ fidx,
    const float* __restrict__ h, const float* __restrict__ Wkp,
    const float* __restrict__ Wout, const float* __restrict__ bout,
    float* __restrict__ y, float* __restrict__ stats)
{
  __shared__ float wkp_s[64*64];        // 16 KB: 64-row chunk of W_kp
  __shared__ float wr_s[NT][KNN*16];    // 16 KB: Phase A w; reused as red_s
  __shared__ float agg_s[NT][KPN*SCC];  // 30 KB, j = p*64+c; reused as h2r_s
  __shared__ int   idx_s[NT][KNN];      // 1 KB
  float (*red_s)[NT*SCC] = (float(*)[NT*SCC])wr_s;   // [8][512] overlay
  float (*h2r_s)[SCC]    = (float(*)[SCC])agg_s;     // [8][64] overlay
  int t = threadIdx.x;
  int w = t >> 6, lane = t & 63;
  int gq = blockIdx.x*NT + w;           // 0..16383 = cloud*NPTS + n
  int cloud = gq >> 13, n = gq & 8191;
  const float* coords = cloud ? cB : cA;
  if (lane < KNN) idx_s[w][lane] = fidx[(size_t)gq*KNN + lane];
  // (no barrier: idx_s[w] is wave-private)
  float qx = coords[(size_t)n*3];
  float qy = coords[(size_t)n*3+1];
  float qz = coords[(size_t)n*3+2];
  for (int e = lane; e < KNN*16; e += 64) {
    int k = e >> 4, p = e & 15;
    int idx = idx_s[w][k];
    float wv = 0.f;
    if (idx >= 0 && p < KPN) {
      float rx = coords[(size_t)idx*3]   - qx;
      float ry = coords[(size_t)idx*3+1] - qy;
      float rz = coords[(size_t)idx*3+2] - qz;
      float dx = rx - kpts[(size_t)p*3];
      float dy = ry - kpts[(size_t)p*3+1];
      float dz = rz - kpts[(size_t)p*3+2];
      float d = sqrtf(fmaf(dx, dx, fmaf(dy, dy, dz*dz)));
      wv = fmaxf(1.0f - d*INV_EXT, 0.0f);
    }
    wr_s[w][k*16 + p] = wv;
  }
  // (no barrier: wr_s[w] is wave-private)
  // Phase A: agg[p][c] for c = lane (acc[15] is a dummy)
  float acc[16];
  #pragma unroll
  for (int p = 0; p < 16; ++p) acc[p] = 0.f;
  for (int k = 0; k < KNN; ++k) {
    int idx = idx_s[w][k];                // wave-uniform
    if (idx < 0) continue;
    float f = h[((size_t)(cloud*NPTS + idx))*SCC + lane];
    const float4* wr = (const float4*)&wr_s[w][k*16];
    #pragma unroll
    for (int g = 0; g < 4; ++g) {
      float4 w4 = wr[g];
      acc[g*4+0] = fmaf(w4.x, f, acc[g*4+0]);
      acc[g*4+1] = fmaf(w4.y, f, acc[g*4+1]);
      acc[g*4+2] = fmaf(w4.z, f, acc[g*4+2]);
      acc[g*4+3] = fmaf(w4.w, f, acc[g*4+3]);
    }
  }
  #pragma unroll
  for (int p = 0; p < KPN; ++p) agg_s[w][p*SCC + lane] = acc[p];
  // Phase B: shared-W contraction (first chunk's barrier publishes agg_s).
  // 64 chunk rows / 8 waves = 8 rows per wave; lane-group jg covers 2 rows.
  int jg = lane >> 4;            // 0..3
  int dq = (lane & 15) * 4;      // dim group
  int jbase = w*8 + jg*2;        // local row base within chunk
  float4 acc4[NT];
  #pragma unroll
  for (int pt = 0; pt < NT; ++pt) acc4[pt] = make_float4(0.f,0.f,0.f,0.f);
  for (int c0 = 0; c0 < KPN*SCC; c0 += 64) {
    __syncthreads();
    {
      const float4* gsrc = (const float4*)(Wkp + (size_t)c0*64);
      float4* ldst = (float4*)wkp_s;
      ldst[t]       = gsrc[t];
      ldst[t + 512] = gsrc[t + 512];
    }
    __syncthreads();
    float4 wv0 = *(const float4*)&wkp_s[(jbase    )*64 + dq];
    float4 wv1 = *(const float4*)&wkp_s[(jbase + 1)*64 + dq];
    #pragma unroll
    for (int pt = 0; pt < NT; ++pt) {
      float2 av = *(const float2*)&agg_s[pt][c0 + jbase];
      acc4[pt].x = fmaf(av.x, wv0.x, acc4[pt].x);
      acc4[pt].y = fmaf(av.x, wv0.y, acc4[pt].y);
      acc4[pt].z = fmaf(av.x, wv0.z, acc4[pt].z);
      acc4[pt].w = fmaf(av.x, wv0.w, acc4[pt].w);
      acc4[pt].x = fmaf(av.y, wv1.x, acc4[pt].x);
      acc4[pt].y = fmaf(av.y, wv1.y, acc4[pt].y);
      acc4[pt].z = fmaf(av.y, wv1.z, acc4[pt].z);
      acc4[pt].w = fmaf(av.y, wv1.w, acc4[pt].w);
    }
  }
  // reduce over jg lane-groups (bits 4,5 of lane)
  #pragma unroll
  for (int pt = 0; pt < NT; ++pt) {
    acc4[pt].x += __shfl_xor(acc4[pt].x, 16); acc4[pt].x += __shfl_xor(acc4[pt].x, 32);
    acc4[pt].y += __shfl_xor(acc4[pt].y, 16); acc4[pt].y += __shfl_xor(acc4[pt].y, 32);
    acc4[pt].z += __shfl_xor(acc4[pt].z, 16); acc4[pt].z += __shfl_xor(acc4[pt].z, 32);
    acc4[pt].w += __shfl_xor(acc4[pt].w, 16); acc4[pt].w += __shfl_xor(acc4[pt].w, 32);
  }
  if (lane < 16) {               // red_s[w] overlays wr_s[w]: wave-private
    #pragma unroll
    for (int pt = 0; pt < NT; ++pt)
      *(float4*)&red_s[w][pt*SCC + dq] = acc4[pt];
  }
  __syncthreads();               // publishes red_s; all Phase-B agg reads done
  {
    int pt = t >> 6, d = t & 63; // one h2 element per thread
    float s = 0.f;
    #pragma unroll
    for (int w8 = 0; w8 < NT; ++w8) s += red_s[w8][pt*SCC + d];
    h2r_s[pt][d] = s;            // safe overlay: agg_s reads all completed
  }
  __syncthreads();
  // Epilogue: y[pt][d] = h2r_s[pt][:] . Wout[:,d] + bout[d]; BN partials.
  {
    int g2 = t >> 8;             // 0..1 -> points g2*4 .. g2*4+3
    int d  = t & 255;
    int pb = g2*4;
    float bb = bout[d];
    float y0 = bb, y1 = bb, y2 = bb, y3 = bb;
    #pragma unroll 4
    for (int c4 = 0; c4 < 16; ++c4) {
      const float* wp = Wout + (size_t)c4*4*OUTC + d;
      float w0 = wp[0], w1 = wp[OUTC], w2 = wp[2*OUTC], w3 = wp[3*OUTC];
      float4 h0 = *(const float4*)&h2r_s[pb+0][c4*4];
      float4 h1 = *(const float4*)&h2r_s[pb+1][c4*4];
      float4 h2v= *(const float4*)&h2r_s[pb+2][c4*4];
      float4 h3 = *(const float4*)&h2r_s[pb+3][c4*4];
      y0 = fmaf(h0.x,w0, fmaf(h0.y,w1, fmaf(h0.z,w2, fmaf(h0.w,w3, y0))));
      y1 = fmaf(h1.x,w0, fmaf(h1.y,w1, fmaf(h1.z,w2, fmaf(h1.w,w3, y1))));
      y2 = fmaf(h2v.x,w0, fmaf(h2v.y,w1, fmaf(h2v.z,w2, fmaf(h2v.w,w3, y2))));
      y3 = fmaf(h3.x,w0, fmaf(h3.y,w1, fmaf(h3.z,w2, fmaf(h3.w,w3, y3))));
    }
    size_t r0 = (size_t)blockIdx.x*NT + pb;
    y[(r0+0)*OUTC + d] = y0;
    y[(r0+1)*OUTC + d] = y1;
    y[(r0+2)*OUTC + d] = y2;
    y[(r0+3)*OUTC + d] = y3;
    float s  = y0 + y1 + y2 + y3;
    float s2 = fmaf(y0,y0, fmaf(y1,y1, fmaf(y2,y2, y3*y3)));
    atomicAdd(&stats[cloud*512 + d], s);
    atomicAdd(&stats[cloud*512 + 256 + d], s2);
  }
}

// ---- BN apply (stats produced by kpconv epilogue atomics) --------------------
__global__ __launch_bounds__(256) void bn_apply_k(
    float* __restrict__ y, const float* __restrict__ stats,
    const float* __restrict__ gamma, const float* __restrict__ beta)
{
  size_t e = (size_t)blockIdx.x*256 + threadIdx.x;
  int c = (int)(e & 255);
  int cloud = (int)(e >> 21);
  float s  = stats[cloud*512 + c];
  float s2 = stats[cloud*512 + 256 + c];
  float mu  = s * (1.0f/NPTS);
  float var = fmaxf(s2 * (1.0f/NPTS) - mu*mu, 0.f);
  float sc = gamma[c] * rsqrtf(var + 1e-5f);
  float sh = beta[c] - mu*sc;
  float v = fmaf(y[e], sc, sh);
  v = v > 0.f ? v : 0.1f*v;
  y[e] = v;
}

// ---- coords tail of output (f32) + stats zeroing (block 192) -----------------
__global__ __launch_bounds__(256) void emit_coords(
    const float* __restrict__ scd, const float* __restrict__ tcd,
    float* __restrict__ out, float* __restrict__ stats)
{
  int b = blockIdx.x;
  int t = threadIdx.x;
  if (b == 192) {
    for (int i = t; i < 1024; i += 256) stats[i] = 0.f;
    return;
  }
  int i = b*256 + t;    // 0..49151
  out[i] = (i < NPTS*3) ? scd[i] : tcd[i - NPTS*3];
}

extern "C" void kernel_launch(void* const* d_in, const int* in_sizes, int n_in,
                              void* d_out, int out_size, void* d_ws, size_t ws_size,
                              hipStream_t stream)
{
  (void)in_sizes; (void)n_in; (void)out_size; (void)ws_size;
  const float* src   = (const float*)d_in[0];
  const float* tgt   = (const float*)d_in[1];
  const float* scd   = (const float*)d_in[2];
  const float* tcd   = (const float*)d_in[3];
  const float* W_in  = (const float*)d_in[4];
  const float* b_in  = (const float*)d_in[5];
  const float* kpts  = (const float*)d_in[6];
  const float* W_kp  = (const float*)d_in[7];
  const float* W_out = (const float*)d_in[8];
  const float* b_out = (const float*)d_in[9];
  const float* gamma = (const float*)d_in[10];
  const float* beta  = (const float*)d_in[11];

  // ---- workspace ----
  char* ws = (char*)d_ws;
  float* h     = (float*)ws;                        // 0..4 MB  [2][8192][64]
  short* fidx  = (short*)(ws + (8u<<20));           // 8..9 MB [16384][32] i16
  float* stats = (float*)(ws + (9u<<20));           // 4 KB

  float* yout = (float*)d_out;

  emit_coords<<<193, 256, 0, stream>>>(scd, tcd, yout + (size_t)2*NPTS*OUTC, stats);
  knn_par<<<4096, 256, 0, stream>>>(scd, tcd, fidx);
  conv_in_k<<<1024, 256, 0, stream>>>(src, tgt, W_in, b_in, h);
  kpconv_fused<<<2048, 512, 0, stream>>>(scd, tcd, kpts, fidx, h, W_kp,
                                         W_out, b_out, yout, stats);
  bn_apply_k<<<16384, 256, 0, stream>>>(yout, stats, gamma, beta);
}

// Round 2
// 340.071 us; speedup vs baseline: 1.1941x; 1.0592x over previous
//
#include <hip/hip_runtime.h>
#include <stdint.h>

#define NPTS 8192
#define KNN 32
#define KPN 15
#define SCC 64
#define OUTC 256
#define R2F 0.0144f              /* radius^2: the reference's in_range mask */
#define INV_EXT (1.0f/0.096f)
#define SCAP 128                 /* per-query survivor cap */
#define NT 8                     /* points per kpconv block */
#define COB 32                   /* rows per conv_out block */

// ---- conv_in: 4 rows per thread (lane = channel), W read once per 4 rows ----
__global__ __launch_bounds__(256) void conv_in_k(
    const float* __restrict__ src, const float* __restrict__ tgt,
    const float* __restrict__ W, const float* __restrict__ b,
    float* __restrict__ h)
{
  int t = threadIdx.x;
  int w = t >> 6, c = t & 63;
  int row = blockIdx.x*16 + w*4;          // 0..16383 = cloud*NPTS+n (no straddle)
  const float* x = (row >> 13) ? tgt : src;
  int n0 = row & 8191;
  const float4* x0 = (const float4*)(x + (size_t)n0*256);
  const float4* x1 = x0 + 64;
  const float4* x2 = x0 + 128;
  const float4* x3 = x0 + 192;
  float bc = b[c];
  float a0 = bc, a1 = bc, a2 = bc, a3 = bc;
  #pragma unroll 4
  for (int k4 = 0; k4 < 64; ++k4) {
    float4 v0 = x0[k4], v1 = x1[k4], v2 = x2[k4], v3 = x3[k4];
    const float* wp = W + (size_t)k4*4*64 + c;
    float w0 = wp[0], w1 = wp[64], w2 = wp[128], w3 = wp[192];
    a0 = fmaf(v0.x,w0,a0); a0 = fmaf(v0.y,w1,a0); a0 = fmaf(v0.z,w2,a0); a0 = fmaf(v0.w,w3,a0);
    a1 = fmaf(v1.x,w0,a1); a1 = fmaf(v1.y,w1,a1); a1 = fmaf(v1.z,w2,a1); a1 = fmaf(v1.w,w3,a1);
    a2 = fmaf(v2.x,w0,a2); a2 = fmaf(v2.y,w1,a2); a2 = fmaf(v2.z,w2,a2); a2 = fmaf(v2.w,w3,a2);
    a3 = fmaf(v3.x,w0,a3); a3 = fmaf(v3.y,w1,a3); a3 = fmaf(v3.z,w2,a3); a3 = fmaf(v3.w,w3,a3);
  }
  float* hr = h + (size_t)row*SCC + c;
  hr[0] = a0; hr[64] = a1; hr[128] = a2; hr[192] = a3;
}

// ---- kNN: one wave per query, LDS-atomic gather + wave rank-select (unchanged)
__global__ __launch_bounds__(256) void knn_par(
    const float* __restrict__ cA, const float* __restrict__ cB,
    short* __restrict__ fidx)
{
  __shared__ float cbuf[2048*3];                  // 24 KB
  __shared__ unsigned long long surv[4][SCAP];    // 4 KB
  __shared__ unsigned int scnt[4];
  int b = blockIdx.x;                // 4096 blocks: cloud(1)|qg(11)
  int cloud = b >> 11;
  int qg = b & 2047;
  const float* coords = cloud ? cB : cA;
  int t = threadIdx.x;
  int w = t >> 6, lane = t & 63;
  int q = qg*4 + w;
  float qx = coords[(size_t)q*3];
  float qy = coords[(size_t)q*3+1];
  float qz = coords[(size_t)q*3+2];
  if (t < 4) scnt[t] = 0u;
  for (int chunk = 0; chunk < 4; ++chunk) {
    __syncthreads();
    int base = chunk*2048;
    const float* gsrc = coords + (size_t)base*3;
    for (int i = t; i < 2048*3; i += 256) cbuf[i] = gsrc[i];
    __syncthreads();
    #pragma unroll 8
    for (int j = 0; j < 32; ++j) {
      int i = lane + 64*j;
      float dx = qx - cbuf[i*3];
      float dy = qy - cbuf[i*3+1];
      float dz = qz - cbuf[i*3+2];
      float d2 = fmaf(dx, dx, fmaf(dy, dy, dz*dz));
      if (d2 <= R2F) {
        unsigned int pos = atomicAdd(&scnt[w], 1u);
        if (pos < SCAP)
          surv[w][pos] = ((unsigned long long)__float_as_uint(d2) << 32)
                         | (unsigned int)(base + i);
      }
    }
  }
  __syncthreads();
  int C = (int)scnt[w]; if (C > SCAP) C = SCAP;
  unsigned long long k0 = (lane      < C) ? surv[w][lane]      : ~0ULL;
  unsigned long long k1 = (lane + 64 < C) ? surv[w][lane + 64] : ~0ULL;
  int r0 = 0, r1 = 0;
  for (int j = 0; j < C; ++j) {
    unsigned long long kj = surv[w][j];       // same addr all lanes: broadcast
    r0 += (kj < k0);
    r1 += (kj < k1);
  }
  size_t g = (size_t)cloud*NPTS + q;
  if (k0 != ~0ULL && r0 < KNN) fidx[g*KNN + r0] = (short)(k0 & 0xffffu);
  if (k1 != ~0ULL && r1 < KNN) fidx[g*KNN + r1] = (short)(k1 & 0xffffu);
  if (lane >= C && lane < KNN) fidx[g*KNN + lane] = (short)-1;  // sentinel fill
}

// ---- fused KPConv, 8 points/block, h2 out -------------------------------------
// Phase A (per wave = per point): agg[pt][j=p*64+c] in LDS; gather unrolled 8.
// Phase B: h2 = agg @ Wkp; W_kp chunk prefetched into REGISTERS while computing
//          the previous chunk (T14 async-STAGE split), then ds_write + barrier.
// LDS 63 KB -> 2 blocks/CU (16 waves/CU).
__global__ __launch_bounds__(512) void kpconv_fused(
    const float* __restrict__ cA, const float* __restrict__ cB,
    const float* __restrict__ kpts, const short* __restrict__ fidx,
    const float* __restrict__ h, const float* __restrict__ Wkp,
    float* __restrict__ h2)
{
  __shared__ float wkp_s[64*64];        // 16 KB: 64-row chunk of W_kp
  __shared__ float wr_s[NT][KNN*16];    // 16 KB: Phase A w; reused as red_s
  __shared__ float agg_s[NT][KPN*SCC];  // 30 KB, j = p*64+c
  __shared__ int   idx_s[NT][KNN];      // 1 KB
  float (*red_s)[NT*SCC] = (float(*)[NT*SCC])wr_s;   // [8][512] overlay
  int t = threadIdx.x;
  int w = t >> 6, lane = t & 63;
  int gq = blockIdx.x*NT + w;           // 0..16383 = cloud*NPTS + n
  int cloud = gq >> 13, n = gq & 8191;
  const float* coords = cloud ? cB : cA;
  if (lane < KNN) idx_s[w][lane] = fidx[(size_t)gq*KNN + lane];
  // (no barrier: idx_s[w] is wave-private)
  float qx = coords[(size_t)n*3];
  float qy = coords[(size_t)n*3+1];
  float qz = coords[(size_t)n*3+2];
  for (int e = lane; e < KNN*16; e += 64) {
    int k = e >> 4, p = e & 15;
    int idx = idx_s[w][k];
    float wv = 0.f;
    if (idx >= 0 && p < KPN) {
      float rx = coords[(size_t)idx*3]   - qx;
      float ry = coords[(size_t)idx*3+1] - qy;
      float rz = coords[(size_t)idx*3+2] - qz;
      float dx = rx - kpts[(size_t)p*3];
      float dy = ry - kpts[(size_t)p*3+1];
      float dz = rz - kpts[(size_t)p*3+2];
      float d = sqrtf(fmaf(dx, dx, fmaf(dy, dy, dz*dz)));
      wv = fmaxf(1.0f - d*INV_EXT, 0.0f);
    }
    wr_s[w][k*16 + p] = wv;
  }
  // (no barrier: wr_s[w] is wave-private)
  // Phase A: agg[p][c] for c = lane (acc[15] is a dummy).
  // Invalid neighbors (idx<0) have all weights == 0, so clamp instead of
  // branching: keeps the 8-deep unrolled gather loads pipelined.
  float acc[16];
  #pragma unroll
  for (int p = 0; p < 16; ++p) acc[p] = 0.f;
  #pragma unroll 8
  for (int k = 0; k < KNN; ++k) {
    int idx = idx_s[w][k];                // wave-uniform
    int ic = idx < 0 ? 0 : idx;
    float f = h[((size_t)(cloud*NPTS + ic))*SCC + lane];
    const float4* wr = (const float4*)&wr_s[w][k*16];
    #pragma unroll
    for (int g = 0; g < 4; ++g) {
      float4 w4 = wr[g];
      acc[g*4+0] = fmaf(w4.x, f, acc[g*4+0]);
      acc[g*4+1] = fmaf(w4.y, f, acc[g*4+1]);
      acc[g*4+2] = fmaf(w4.z, f, acc[g*4+2]);
      acc[g*4+3] = fmaf(w4.w, f, acc[g*4+3]);
    }
  }
  #pragma unroll
  for (int p = 0; p < KPN; ++p) agg_s[w][p*SCC + lane] = acc[p];
  // Phase B: shared-W contraction with register-prefetched staging.
  // 64 chunk rows / 8 waves = 8 rows per wave; lane-group jg covers 2 rows.
  int jg = lane >> 4;            // 0..3
  int dq = (lane & 15) * 4;      // dim group
  int jbase = w*8 + jg*2;        // local row base within chunk
  float4 acc4[NT];
  #pragma unroll
  for (int pt = 0; pt < NT; ++pt) acc4[pt] = make_float4(0.f,0.f,0.f,0.f);
  float4 nx0, nx1;
  {
    const float4* gsrc = (const float4*)Wkp;     // chunk 0
    nx0 = gsrc[t]; nx1 = gsrc[t + 512];
  }
  for (int c0 = 0; c0 < KPN*SCC; c0 += 64) {
    __syncthreads();             // all waves done reading wkp_s (prev chunk);
                                 // first iter: publishes agg_s too
    ((float4*)wkp_s)[t]       = nx0;
    ((float4*)wkp_s)[t + 512] = nx1;
    __syncthreads();             // publish wkp_s
    if (c0 + 64 < KPN*SCC) {     // issue next chunk early: overlaps compute
      const float4* gsrc = (const float4*)(Wkp + (size_t)(c0 + 64)*64);
      nx0 = gsrc[t]; nx1 = gsrc[t + 512];
    }
    float4 wv0 = *(const float4*)&wkp_s[(jbase    )*64 + dq];
    float4 wv1 = *(const float4*)&wkp_s[(jbase + 1)*64 + dq];
    #pragma unroll
    for (int pt = 0; pt < NT; ++pt) {
      float2 av = *(const float2*)&agg_s[pt][c0 + jbase];
      acc4[pt].x = fmaf(av.x, wv0.x, acc4[pt].x);
      acc4[pt].y = fmaf(av.x, wv0.y, acc4[pt].y);
      acc4[pt].z = fmaf(av.x, wv0.z, acc4[pt].z);
      acc4[pt].w = fmaf(av.x, wv0.w, acc4[pt].w);
      acc4[pt].x = fmaf(av.y, wv1.x, acc4[pt].x);
      acc4[pt].y = fmaf(av.y, wv1.y, acc4[pt].y);
      acc4[pt].z = fmaf(av.y, wv1.z, acc4[pt].z);
      acc4[pt].w = fmaf(av.y, wv1.w, acc4[pt].w);
    }
  }
  // reduce over jg lane-groups (bits 4,5 of lane)
  #pragma unroll
  for (int pt = 0; pt < NT; ++pt) {
    acc4[pt].x += __shfl_xor(acc4[pt].x, 16); acc4[pt].x += __shfl_xor(acc4[pt].x, 32);
    acc4[pt].y += __shfl_xor(acc4[pt].y, 16); acc4[pt].y += __shfl_xor(acc4[pt].y, 32);
    acc4[pt].z += __shfl_xor(acc4[pt].z, 16); acc4[pt].z += __shfl_xor(acc4[pt].z, 32);
    acc4[pt].w += __shfl_xor(acc4[pt].w, 16); acc4[pt].w += __shfl_xor(acc4[pt].w, 32);
  }
  if (lane < 16) {               // red_s[w] overlays wr_s[w]: wave-private
    #pragma unroll
    for (int pt = 0; pt < NT; ++pt)
      *(float4*)&red_s[w][pt*SCC + dq] = acc4[pt];
  }
  __syncthreads();               // publishes red_s; all Phase-B reads done
  {
    int pt = t >> 6, d = t & 63; // one h2 element per thread, coalesced store
    float s = 0.f;
    #pragma unroll
    for (int w8 = 0; w8 < NT; ++w8) s += red_s[w8][pt*SCC + d];
    h2[((size_t)blockIdx.x*NT + pt)*SCC + d] = s;
  }
}

// ---- conv_out + bias + BN partial stats: tiled GEMM, all operands in LDS -----
// 512 blocks x 512 thr; block = 32 rows. W_out (64 KB) staged ONCE per block.
// Per thread: col d, 16 rows, 1024 FMA, all reads from LDS.
// Stats: LDS cross-rg reduce -> 1 atomic per (block, channel) = 256/address.
__global__ __launch_bounds__(512) void conv_out_bn(
    const float* __restrict__ h2, const float* __restrict__ W,
    const float* __restrict__ b, float* __restrict__ y,
    float* __restrict__ stats)
{
  __shared__ float w_s[SCC*OUTC];      // 64 KB
  __shared__ float h_s[COB][SCC];      // 8 KB
  __shared__ float rs_s[2][OUTC];      // 2 KB
  __shared__ float rs2_s[2][OUTC];     // 2 KB
  int t = threadIdx.x;
  int d = t & 255, rg = t >> 8;        // rg in {0,1}: 16-row halves
  int row0 = blockIdx.x*COB;
  int cloud = (int)(blockIdx.x >> 8);  // 256 blocks per cloud
  {
    const float4* gw = (const float4*)W;
    float4* lw = (float4*)w_s;
    #pragma unroll
    for (int i = 0; i < 8; ++i) lw[t + 512*i] = gw[t + 512*i];
    const float4* gh = (const float4*)(h2 + (size_t)row0*SCC);
    ((float4*)h_s)[t] = gh[t];
  }
  __syncthreads();
  float acc[16];
  float bb = b[d];
  #pragma unroll
  for (int r = 0; r < 16; ++r) acc[r] = bb;
  int rb = rg*16;
  #pragma unroll 4
  for (int c4 = 0; c4 < 16; ++c4) {
    float w0 = w_s[(c4*4+0)*OUTC + d];
    float w1 = w_s[(c4*4+1)*OUTC + d];
    float w2 = w_s[(c4*4+2)*OUTC + d];
    float w3 = w_s[(c4*4+3)*OUTC + d];
    #pragma unroll
    for (int r = 0; r < 16; ++r) {
      float4 hv = *(const float4*)&h_s[rb + r][c4*4];
      acc[r] = fmaf(hv.x,w0, fmaf(hv.y,w1, fmaf(hv.z,w2, fmaf(hv.w,w3, acc[r]))));
    }
  }
  float s = 0.f, s2 = 0.f;
  #pragma unroll
  for (int r = 0; r < 16; ++r) {
    float v = acc[r];
    y[((size_t)row0 + rb + r)*OUTC + d] = v;
    s += v; s2 = fmaf(v, v, s2);
  }
  rs_s[rg][d] = s; rs2_s[rg][d] = s2;
  __syncthreads();
  if (rg == 0) {
    atomicAdd(&stats[cloud*512 + d],       s  + rs_s[1][d]);
    atomicAdd(&stats[cloud*512 + 256 + d], s2 + rs2_s[1][d]);
  }
}

// ---- BN apply ----------------------------------------------------------------
__global__ __launch_bounds__(256) void bn_apply_k(
    float* __restrict__ y, const float* __restrict__ stats,
    const float* __restrict__ gamma, const float* __restrict__ beta)
{
  size_t e = (size_t)blockIdx.x*256 + threadIdx.x;
  int c = (int)(e & 255);
  int cloud = (int)(e >> 21);
  float s  = stats[cloud*512 + c];
  float s2 = stats[cloud*512 + 256 + c];
  float mu  = s * (1.0f/NPTS);
  float var = fmaxf(s2 * (1.0f/NPTS) - mu*mu, 0.f);
  float sc = gamma[c] * rsqrtf(var + 1e-5f);
  float sh = beta[c] - mu*sc;
  float v = fmaf(y[e], sc, sh);
  v = v > 0.f ? v : 0.1f*v;
  y[e] = v;
}

// ---- coords tail of output (f32) + stats zeroing (block 192) -----------------
__global__ __launch_bounds__(256) void emit_coords(
    const float* __restrict__ scd, const float* __restrict__ tcd,
    float* __restrict__ out, float* __restrict__ stats)
{
  int b = blockIdx.x;
  int t = threadIdx.x;
  if (b == 192) {
    for (int i = t; i < 1024; i += 256) stats[i] = 0.f;
    return;
  }
  int i = b*256 + t;    // 0..49151
  out[i] = (i < NPTS*3) ? scd[i] : tcd[i - NPTS*3];
}

extern "C" void kernel_launch(void* const* d_in, const int* in_sizes, int n_in,
                              void* d_out, int out_size, void* d_ws, size_t ws_size,
                              hipStream_t stream)
{
  (void)in_sizes; (void)n_in; (void)out_size; (void)ws_size;
  const float* src   = (const float*)d_in[0];
  const float* tgt   = (const float*)d_in[1];
  const float* scd   = (const float*)d_in[2];
  const float* tcd   = (const float*)d_in[3];
  const float* W_in  = (const float*)d_in[4];
  const float* b_in  = (const float*)d_in[5];
  const float* kpts  = (const float*)d_in[6];
  const float* W_kp  = (const float*)d_in[7];
  const float* W_out = (const float*)d_in[8];
  const float* b_out = (const float*)d_in[9];
  const float* gamma = (const float*)d_in[10];
  const float* beta  = (const float*)d_in[11];

  // ---- workspace ----
  char* ws = (char*)d_ws;
  float* h     = (float*)ws;                        // 0..4 MB  [2][8192][64]
  float* h2    = (float*)(ws + (4u<<20));           // 4..8 MB  [2][8192][64]
  short* fidx  = (short*)(ws + (8u<<20));           // 8..9 MB [16384][32] i16
  float* stats = (float*)(ws + (9u<<20));           // 4 KB

  float* yout = (float*)d_out;

  emit_coords<<<193, 256, 0, stream>>>(scd, tcd, yout + (size_t)2*NPTS*OUTC, stats);
  knn_par<<<4096, 256, 0, stream>>>(scd, tcd, fidx);
  conv_in_k<<<1024, 256, 0, stream>>>(src, tgt, W_in, b_in, h);
  kpconv_fused<<<2048, 512, 0, stream>>>(scd, tcd, kpts, fidx, h, W_kp, h2);
  conv_out_bn<<<512, 512, 0, stream>>>(h2, W_out, b_out, yout, stats);
  bn_apply_k<<<16384, 256, 0, stream>>>(yout, stats, gamma, beta);
}

// Round 3
// 299.382 us; speedup vs baseline: 1.3564x; 1.1359x over previous
//
#include <hip/hip_runtime.h>
#include <stdint.h>

#define NPTS 8192
#define KNN 32
#define KPN 15
#define SCC 64
#define OUTC 256
#define R2F 0.0144f              /* radius^2: the reference's in_range mask */
#define INV_EXT (1.0f/0.096f)
#define SCAP 128                 /* per-query survivor cap */
#define NT 8                     /* points per kpconv block */
#define COB 32                   /* rows per conv_out block */

// ---- conv_in: 4 rows per thread (lane = channel), W read once per 4 rows ----
__global__ __launch_bounds__(256) void conv_in_k(
    const float* __restrict__ src, const float* __restrict__ tgt,
    const float* __restrict__ W, const float* __restrict__ b,
    float* __restrict__ h)
{
  int t = threadIdx.x;
  int w = t >> 6, c = t & 63;
  int row = blockIdx.x*16 + w*4;          // 0..16383 = cloud*NPTS+n (no straddle)
  const float* x = (row >> 13) ? tgt : src;
  int n0 = row & 8191;
  const float4* x0 = (const float4*)(x + (size_t)n0*256);
  const float4* x1 = x0 + 64;
  const float4* x2 = x0 + 128;
  const float4* x3 = x0 + 192;
  float bc = b[c];
  float a0 = bc, a1 = bc, a2 = bc, a3 = bc;
  #pragma unroll 4
  for (int k4 = 0; k4 < 64; ++k4) {
    float4 v0 = x0[k4], v1 = x1[k4], v2 = x2[k4], v3 = x3[k4];
    const float* wp = W + (size_t)k4*4*64 + c;
    float w0 = wp[0], w1 = wp[64], w2 = wp[128], w3 = wp[192];
    a0 = fmaf(v0.x,w0,a0); a0 = fmaf(v0.y,w1,a0); a0 = fmaf(v0.z,w2,a0); a0 = fmaf(v0.w,w3,a0);
    a1 = fmaf(v1.x,w0,a1); a1 = fmaf(v1.y,w1,a1); a1 = fmaf(v1.z,w2,a1); a1 = fmaf(v1.w,w3,a1);
    a2 = fmaf(v2.x,w0,a2); a2 = fmaf(v2.y,w1,a2); a2 = fmaf(v2.z,w2,a2); a2 = fmaf(v2.w,w3,a2);
    a3 = fmaf(v3.x,w0,a3); a3 = fmaf(v3.y,w1,a3); a3 = fmaf(v3.z,w2,a3); a3 = fmaf(v3.w,w3,a3);
  }
  float* hr = h + (size_t)row*SCC + c;
  hr[0] = a0; hr[64] = a1; hr[128] = a2; hr[192] = a3;
}

// ---- kNN: one wave per query, LDS-atomic gather + wave rank-select (unchanged)
__global__ __launch_bounds__(256) void knn_par(
    const float* __restrict__ cA, const float* __restrict__ cB,
    short* __restrict__ fidx)
{
  __shared__ float cbuf[2048*3];                  // 24 KB
  __shared__ unsigned long long surv[4][SCAP];    // 4 KB
  __shared__ unsigned int scnt[4];
  int b = blockIdx.x;                // 4096 blocks: cloud(1)|qg(11)
  int cloud = b >> 11;
  int qg = b & 2047;
  const float* coords = cloud ? cB : cA;
  int t = threadIdx.x;
  int w = t >> 6, lane = t & 63;
  int q = qg*4 + w;
  float qx = coords[(size_t)q*3];
  float qy = coords[(size_t)q*3+1];
  float qz = coords[(size_t)q*3+2];
  if (t < 4) scnt[t] = 0u;
  for (int chunk = 0; chunk < 4; ++chunk) {
    __syncthreads();
    int base = chunk*2048;
    const float* gsrc = coords + (size_t)base*3;
    for (int i = t; i < 2048*3; i += 256) cbuf[i] = gsrc[i];
    __syncthreads();
    #pragma unroll 8
    for (int j = 0; j < 32; ++j) {
      int i = lane + 64*j;
      float dx = qx - cbuf[i*3];
      float dy = qy - cbuf[i*3+1];
      float dz = qz - cbuf[i*3+2];
      float d2 = fmaf(dx, dx, fmaf(dy, dy, dz*dz));
      if (d2 <= R2F) {
        unsigned int pos = atomicAdd(&scnt[w], 1u);
        if (pos < SCAP)
          surv[w][pos] = ((unsigned long long)__float_as_uint(d2) << 32)
                         | (unsigned int)(base + i);
      }
    }
  }
  __syncthreads();
  int C = (int)scnt[w]; if (C > SCAP) C = SCAP;
  unsigned long long k0 = (lane      < C) ? surv[w][lane]      : ~0ULL;
  unsigned long long k1 = (lane + 64 < C) ? surv[w][lane + 64] : ~0ULL;
  int r0 = 0, r1 = 0;
  for (int j = 0; j < C; ++j) {
    unsigned long long kj = surv[w][j];       // same addr all lanes: broadcast
    r0 += (kj < k0);
    r1 += (kj < k1);
  }
  size_t g = (size_t)cloud*NPTS + q;
  if (k0 != ~0ULL && r0 < KNN) fidx[g*KNN + r0] = (short)(k0 & 0xffffu);
  if (k1 != ~0ULL && r1 < KNN) fidx[g*KNN + r1] = (short)(k1 & 0xffffu);
  if (lane >= C && lane < KNN) fidx[g*KNN + lane] = (short)-1;  // sentinel fill
}

// ---- fused KPConv v3, 8 points/block, h2 out ---------------------------------
// Weights + neighbor idx live in REGISTERS, broadcast via v_readlane (no LDS).
// Phase B reads W_kp rows DIRECTLY from global (L2): each LDS-staged word was
// consumed by exactly one wave anyway, so staging bought nothing. K-loop is
// barrier-free with depth-1 register prefetch.
// LDS = agg_s only (30 KB, red_s overlaid) -> 3-4 blocks/CU; 3 barriers total.
__global__ __launch_bounds__(512) void kpconv_fused(
    const float* __restrict__ cA, const float* __restrict__ cB,
    const float* __restrict__ kpts, const short* __restrict__ fidx,
    const float* __restrict__ h, const float* __restrict__ Wkp,
    float* __restrict__ h2)
{
  __shared__ float agg_s[NT][KPN*SCC];               // 30 KB, j = p*64+c
  float (*red_s)[NT*SCC] = (float(*)[NT*SCC])agg_s;  // 16 KB overlay (epilogue)
  int t = threadIdx.x;
  int w = t >> 6, lane = t & 63;
  int gq = blockIdx.x*NT + w;           // 0..16383 = cloud*NPTS + n
  int cloud = gq >> 13, n = gq & 8191;
  const float* coords = cloud ? cB : cA;
  int idxreg = fidx[(size_t)gq*KNN + (lane & 31)];   // lanes 32-63 mirror 0-31
  float qx = coords[(size_t)n*3];
  float qy = coords[(size_t)n*3+1];
  float qz = coords[(size_t)n*3+2];
  // weights in registers: wreg[i] = infl[k = i*4 + (lane>>4)][p = lane&15]
  int p = lane & 15;
  int pc = p < KPN ? p : 0;             // clamp: p==15 lane reads kpts[0], wv=0
  float kpx = kpts[pc*3], kpy = kpts[pc*3+1], kpz = kpts[pc*3+2];
  float wreg[8];
  #pragma unroll
  for (int i = 0; i < 8; ++i) {
    int k = i*4 + (lane >> 4);
    int idx = __shfl(idxreg, k);        // per-lane k: bpermute is fine here
    float wv = 0.f;
    if (idx >= 0 && p < KPN) {
      float rx = coords[(size_t)idx*3]   - qx;
      float ry = coords[(size_t)idx*3+1] - qy;
      float rz = coords[(size_t)idx*3+2] - qz;
      float dx = rx - kpx, dy = ry - kpy, dz = rz - kpz;
      float d = sqrtf(fmaf(dx, dx, fmaf(dy, dy, dz*dz)));
      wv = fmaxf(1.0f - d*INV_EXT, 0.0f);
    }
    wreg[i] = wv;
  }
  // Phase A: agg[p][c] for c = lane; weights broadcast via readlane (SGPR
  // FMA operand), acc[15] is a dummy. idx<0 rows have all-zero weights.
  float acc[16];
  #pragma unroll
  for (int pp = 0; pp < 16; ++pp) acc[pp] = 0.f;
  #pragma unroll
  for (int k = 0; k < KNN; ++k) {
    int idx = __builtin_amdgcn_readlane(idxreg, k);   // wave-uniform
    int ic = idx < 0 ? 0 : idx;
    float f = h[((size_t)(cloud*NPTS + ic))*SCC + lane];
    #pragma unroll
    for (int g = 0; g < 16; ++g) {
      float wg = __int_as_float(
          __builtin_amdgcn_readlane(__float_as_int(wreg[k >> 2]),
                                    ((k & 3) << 4) | g));
      acc[g] = fmaf(wg, f, acc[g]);
    }
  }
  #pragma unroll
  for (int pp = 0; pp < KPN; ++pp) agg_s[w][pp*SCC + lane] = acc[pp];
  // Phase B: h2 = agg @ Wkp. Wave w owns rows w*8..w*8+7 of each 64-row chunk,
  // read straight from global (L2-resident, each element read once per block).
  int jg = lane >> 4;            // 0..3
  int dq = (lane & 15) * 4;      // dim group
  int jbase = w*8 + jg*2;        // rows within chunk
  float4 acc4[NT];
  #pragma unroll
  for (int pt = 0; pt < NT; ++pt) acc4[pt] = make_float4(0.f,0.f,0.f,0.f);
  float4 nx0 = *(const float4*)&Wkp[(size_t)(jbase    )*SCC + dq];
  float4 nx1 = *(const float4*)&Wkp[(size_t)(jbase + 1)*SCC + dq];
  __syncthreads();               // publish agg_s (the ONLY pre-epilogue barrier)
  for (int c0 = 0; c0 < KPN*SCC; c0 += 64) {
    float4 wv0 = nx0, wv1 = nx1;
    if (c0 + 64 < KPN*SCC) {     // depth-1 prefetch of next chunk's rows
      nx0 = *(const float4*)&Wkp[(size_t)(c0 + 64 + jbase    )*SCC + dq];
      nx1 = *(const float4*)&Wkp[(size_t)(c0 + 64 + jbase + 1)*SCC + dq];
    }
    #pragma unroll
    for (int pt = 0; pt < NT; ++pt) {
      float2 av = *(const float2*)&agg_s[pt][c0 + jbase];
      acc4[pt].x = fmaf(av.x, wv0.x, acc4[pt].x);
      acc4[pt].y = fmaf(av.x, wv0.y, acc4[pt].y);
      acc4[pt].z = fmaf(av.x, wv0.z, acc4[pt].z);
      acc4[pt].w = fmaf(av.x, wv0.w, acc4[pt].w);
      acc4[pt].x = fmaf(av.y, wv1.x, acc4[pt].x);
      acc4[pt].y = fmaf(av.y, wv1.y, acc4[pt].y);
      acc4[pt].z = fmaf(av.y, wv1.z, acc4[pt].z);
      acc4[pt].w = fmaf(av.y, wv1.w, acc4[pt].w);
    }
  }
  // reduce over jg lane-groups (bits 4,5 of lane)
  #pragma unroll
  for (int pt = 0; pt < NT; ++pt) {
    acc4[pt].x += __shfl_xor(acc4[pt].x, 16); acc4[pt].x += __shfl_xor(acc4[pt].x, 32);
    acc4[pt].y += __shfl_xor(acc4[pt].y, 16); acc4[pt].y += __shfl_xor(acc4[pt].y, 32);
    acc4[pt].z += __shfl_xor(acc4[pt].z, 16); acc4[pt].z += __shfl_xor(acc4[pt].z, 32);
    acc4[pt].w += __shfl_xor(acc4[pt].w, 16); acc4[pt].w += __shfl_xor(acc4[pt].w, 32);
  }
  __syncthreads();               // all agg_s reads done -> red_s overlay safe
  if (lane < 16) {
    #pragma unroll
    for (int pt = 0; pt < NT; ++pt)
      *(float4*)&red_s[w][pt*SCC + dq] = acc4[pt];
  }
  __syncthreads();               // publish red_s
  {
    int pt = t >> 6, d = t & 63; // one h2 element per thread, coalesced store
    float s = 0.f;
    #pragma unroll
    for (int w8 = 0; w8 < NT; ++w8) s += red_s[w8][pt*SCC + d];
    h2[((size_t)blockIdx.x*NT + pt)*SCC + d] = s;
  }
}

// ---- conv_out + bias + BN partial stats: tiled GEMM, all operands in LDS -----
__global__ __launch_bounds__(512) void conv_out_bn(
    const float* __restrict__ h2, const float* __restrict__ W,
    const float* __restrict__ b, float* __restrict__ y,
    float* __restrict__ stats)
{
  __shared__ float w_s[SCC*OUTC];      // 64 KB
  __shared__ float h_s[COB][SCC];      // 8 KB
  __shared__ float rs_s[2][OUTC];      // 2 KB
  __shared__ float rs2_s[2][OUTC];     // 2 KB
  int t = threadIdx.x;
  int d = t & 255, rg = t >> 8;        // rg in {0,1}: 16-row halves
  int row0 = blockIdx.x*COB;
  int cloud = (int)(blockIdx.x >> 8);  // 256 blocks per cloud
  {
    const float4* gw = (const float4*)W;
    float4* lw = (float4*)w_s;
    #pragma unroll
    for (int i = 0; i < 8; ++i) lw[t + 512*i] = gw[t + 512*i];
    const float4* gh = (const float4*)(h2 + (size_t)row0*SCC);
    ((float4*)h_s)[t] = gh[t];
  }
  __syncthreads();
  float acc[16];
  float bb = b[d];
  #pragma unroll
  for (int r = 0; r < 16; ++r) acc[r] = bb;
  int rb = rg*16;
  #pragma unroll 4
  for (int c4 = 0; c4 < 16; ++c4) {
    float w0 = w_s[(c4*4+0)*OUTC + d];
    float w1 = w_s[(c4*4+1)*OUTC + d];
    float w2 = w_s[(c4*4+2)*OUTC + d];
    float w3 = w_s[(c4*4+3)*OUTC + d];
    #pragma unroll
    for (int r = 0; r < 16; ++r) {
      float4 hv = *(const float4*)&h_s[rb + r][c4*4];
      acc[r] = fmaf(hv.x,w0, fmaf(hv.y,w1, fmaf(hv.z,w2, fmaf(hv.w,w3, acc[r]))));
    }
  }
  float s = 0.f, s2 = 0.f;
  #pragma unroll
  for (int r = 0; r < 16; ++r) {
    float v = acc[r];
    y[((size_t)row0 + rb + r)*OUTC + d] = v;
    s += v; s2 = fmaf(v, v, s2);
  }
  rs_s[rg][d] = s; rs2_s[rg][d] = s2;
  __syncthreads();
  if (rg == 0) {
    atomicAdd(&stats[cloud*512 + d],       s  + rs_s[1][d]);
    atomicAdd(&stats[cloud*512 + 256 + d], s2 + rs2_s[1][d]);
  }
}

// ---- BN apply ----------------------------------------------------------------
__global__ __launch_bounds__(256) void bn_apply_k(
    float* __restrict__ y, const float* __restrict__ stats,
    const float* __restrict__ gamma, const float* __restrict__ beta)
{
  size_t e = (size_t)blockIdx.x*256 + threadIdx.x;
  int c = (int)(e & 255);
  int cloud = (int)(e >> 21);
  float s  = stats[cloud*512 + c];
  float s2 = stats[cloud*512 + 256 + c];
  float mu  = s * (1.0f/NPTS);
  float var = fmaxf(s2 * (1.0f/NPTS) - mu*mu, 0.f);
  float sc = gamma[c] * rsqrtf(var + 1e-5f);
  float sh = beta[c] - mu*sc;
  float v = fmaf(y[e], sc, sh);
  v = v > 0.f ? v : 0.1f*v;
  y[e] = v;
}

// ---- coords tail of output (f32) + stats zeroing (block 192) -----------------
__global__ __launch_bounds__(256) void emit_coords(
    const float* __restrict__ scd, const float* __restrict__ tcd,
    float* __restrict__ out, float* __restrict__ stats)
{
  int b = blockIdx.x;
  int t = threadIdx.x;
  if (b == 192) {
    for (int i = t; i < 1024; i += 256) stats[i] = 0.f;
    return;
  }
  int i = b*256 + t;    // 0..49151
  out[i] = (i < NPTS*3) ? scd[i] : tcd[i - NPTS*3];
}

extern "C" void kernel_launch(void* const* d_in, const int* in_sizes, int n_in,
                              void* d_out, int out_size, void* d_ws, size_t ws_size,
                              hipStream_t stream)
{
  (void)in_sizes; (void)n_in; (void)out_size; (void)ws_size;
  const float* src   = (const float*)d_in[0];
  const float* tgt   = (const float*)d_in[1];
  const float* scd   = (const float*)d_in[2];
  const float* tcd   = (const float*)d_in[3];
  const float* W_in  = (const float*)d_in[4];
  const float* b_in  = (const float*)d_in[5];
  const float* kpts  = (const float*)d_in[6];
  const float* W_kp  = (const float*)d_in[7];
  const float* W_out = (const float*)d_in[8];
  const float* b_out = (const float*)d_in[9];
  const float* gamma = (const float*)d_in[10];
  const float* beta  = (const float*)d_in[11];

  // ---- workspace ----
  char* ws = (char*)d_ws;
  float* h     = (float*)ws;                        // 0..4 MB  [2][8192][64]
  float* h2    = (float*)(ws + (4u<<20));           // 4..8 MB  [2][8192][64]
  short* fidx  = (short*)(ws + (8u<<20));           // 8..9 MB [16384][32] i16
  float* stats = (float*)(ws + (9u<<20));           // 4 KB

  float* yout = (float*)d_out;

  emit_coords<<<193, 256, 0, stream>>>(scd, tcd, yout + (size_t)2*NPTS*OUTC, stats);
  knn_par<<<4096, 256, 0, stream>>>(scd, tcd, fidx);
  conv_in_k<<<1024, 256, 0, stream>>>(src, tgt, W_in, b_in, h);
  kpconv_fused<<<2048, 512, 0, stream>>>(scd, tcd, kpts, fidx, h, W_kp, h2);
  conv_out_bn<<<512, 512, 0, stream>>>(h2, W_out, b_out, yout, stats);
  bn_apply_k<<<16384, 256, 0, stream>>>(yout, stats, gamma, beta);
}